// Round 7
// baseline (918.391 us; speedup 1.0000x reference)
//
#include <hip/hip_runtime.h>
#include <cstdint>
#include <cstddef>

#define D_MODEL 1024
#define D_FF    2048
#define N_EXP   8
#define NTOK    4096          // B*S
#define NASSIGN (NTOK * 2)    // top-2
#define MAXTILE 72            // sum ceil(cnt_e/128) <= 64+7

typedef __bf16 bf16_t;
typedef bf16_t bf16x8 __attribute__((ext_vector_type(8)));
typedef float  f32x4  __attribute__((ext_vector_type(4)));

typedef __attribute__((address_space(3))) void       lds_void;
typedef const __attribute__((address_space(1))) void gl_void;

__device__ __forceinline__ unsigned short f2b(float f) {
  union { float f; unsigned u; } v; v.f = f;
  unsigned u = v.u;
  unsigned r = (u + 0x7FFFu + ((u >> 16) & 1u)) >> 16;  // RNE
  return (unsigned short)r;
}
__device__ __forceinline__ float b2f(unsigned short b) {
  union { unsigned u; float f; } v; v.u = ((unsigned)b) << 16; return v.f;
}

// ---------------- Prep: w1 transpose | w2 transpose | router, one launch ----------------
// Pair-pipelined transpose: 2 adjacent 64x64 tiles per block; all 8 global
// loads issued up-front (512 B contiguous per row); bf16 pairs packed in u32
// LDS [64][33] (phase-2 reads are broadcast-pairs, max 2-way = free);
// 3 barriers per 2 tiles.
__device__ __forceinline__ void transpose_pair(
    const float* __restrict__ ein, unsigned short* __restrict__ eout,
    int R, int C, int c00, int r0, unsigned* T0, unsigned* T1, int tid)
{
  const int g = tid >> 4;        // 0..15
  const int m = tid & 15;        // 0..15
  const int sh = (g & 1) * 16;

  float4 v[2][4];
  #pragma unroll
  for (int t = 0; t < 2; ++t)
    #pragma unroll
    for (int i = 0; i < 4; ++i)
      v[t][i] = *(const float4*)(ein + (size_t)(r0 + i * 16 + g) * C + (c00 + t * 64) + m * 4);

  #pragma unroll
  for (int i = 0; i < 4; ++i) {
    unsigned lo = (unsigned)f2b(v[0][i].x) | ((unsigned)f2b(v[0][i].y) << 16);
    unsigned hi = (unsigned)f2b(v[0][i].z) | ((unsigned)f2b(v[0][i].w) << 16);
    unsigned* p = T0 + (i * 16 + g) * 33 + m * 2;
    p[0] = lo; p[1] = hi;
  }
  __syncthreads();
  // tile1 pack (independent of T0 reads below; lands before barrier 2)
  #pragma unroll
  for (int i = 0; i < 4; ++i) {
    unsigned lo = (unsigned)f2b(v[1][i].x) | ((unsigned)f2b(v[1][i].y) << 16);
    unsigned hi = (unsigned)f2b(v[1][i].z) | ((unsigned)f2b(v[1][i].w) << 16);
    unsigned* p = T1 + (i * 16 + g) * 33 + m * 2;
    p[0] = lo; p[1] = hi;
  }
  // tile0 phase-2
  #pragma unroll
  for (int i = 0; i < 4; ++i) {
    int c = i * 16 + g;
    ushort4 o;
    o.x = (unsigned short)(T0[(4 * m + 0) * 33 + (c >> 1)] >> sh);
    o.y = (unsigned short)(T0[(4 * m + 1) * 33 + (c >> 1)] >> sh);
    o.z = (unsigned short)(T0[(4 * m + 2) * 33 + (c >> 1)] >> sh);
    o.w = (unsigned short)(T0[(4 * m + 3) * 33 + (c >> 1)] >> sh);
    *(ushort4*)(eout + (size_t)(c00 + c) * R + r0 + m * 4) = o;
  }
  __syncthreads();
  #pragma unroll
  for (int i = 0; i < 4; ++i) {
    int c = i * 16 + g;
    ushort4 o;
    o.x = (unsigned short)(T1[(4 * m + 0) * 33 + (c >> 1)] >> sh);
    o.y = (unsigned short)(T1[(4 * m + 1) * 33 + (c >> 1)] >> sh);
    o.z = (unsigned short)(T1[(4 * m + 2) * 33 + (c >> 1)] >> sh);
    o.w = (unsigned short)(T1[(4 * m + 3) * 33 + (c >> 1)] >> sh);
    *(ushort4*)(eout + (size_t)(c00 + c + 64) * R + r0 + m * 4) = o;
  }
}

__global__ __launch_bounds__(256) void prep_k(
    const float* __restrict__ x, const float* __restrict__ gw,
    const float* __restrict__ w1, const float* __restrict__ w2,
    unsigned short* __restrict__ w1t, unsigned short* __restrict__ w2t,
    int* __restrict__ eidx, float* __restrict__ ewt)
{
  __shared__ unsigned T[2][64 * 33];
  const int bid = blockIdx.x;
  const int tid = threadIdx.x;

  if (bid < 2048) {
    // w1: [e][1024][2048] -> [e][2048][1024]; pairs along C: bx2 0..15, by 0..15
    int e = bid >> 8, rem = bid & 255;
    int bx2 = rem & 15, by = rem >> 4;
    transpose_pair(w1 + (size_t)e * D_MODEL * D_FF,
                   w1t + (size_t)e * D_MODEL * D_FF,
                   D_MODEL, D_FF, bx2 * 128, by * 64, T[0], T[1], tid);
    return;
  }
  if (bid < 4096) {
    // w2: [e][2048][1024] -> [e][1024][2048]; pairs along C: bx2 0..7, by 0..31
    int b = bid - 2048;
    int e = b >> 8, rem = b & 255;
    int bx2 = rem & 7, by = rem >> 3;
    transpose_pair(w2 + (size_t)e * D_MODEL * D_FF,
                   w2t + (size_t)e * D_MODEL * D_FF,
                   D_FF, D_MODEL, bx2 * 128, by * 64, T[0], T[1], tid);
    return;
  }
  // router: fp32 logits, top-2, softmax
  const int rb = bid - 4096;
  const int wv = tid >> 6, lane = tid & 63;
  const int token = rb * 4 + wv;
  const float4* xr4 = (const float4*)(x + (size_t)token * D_MODEL);
  const float4* gw4 = (const float4*)gw;

  float acc[8] = {};
  #pragma unroll
  for (int it = 0; it < 4; ++it) {
    float4 xv = xr4[it * 64 + lane];
    int d0 = it * 256 + lane * 4;
    #pragma unroll
    for (int i = 0; i < 4; ++i) {
      int d = d0 + i;
      float4 g0 = gw4[d * 2];
      float4 g1 = gw4[d * 2 + 1];
      float xs = (i == 0) ? xv.x : (i == 1) ? xv.y : (i == 2) ? xv.z : xv.w;
      acc[0] += xs * g0.x; acc[1] += xs * g0.y;
      acc[2] += xs * g0.z; acc[3] += xs * g0.w;
      acc[4] += xs * g1.x; acc[5] += xs * g1.y;
      acc[6] += xs * g1.z; acc[7] += xs * g1.w;
    }
  }
  #pragma unroll
  for (int m = 1; m < 64; m <<= 1) {
    #pragma unroll
    for (int k = 0; k < 8; ++k) acc[k] += __shfl_xor(acc[k], m);
  }
  if (lane == 0) {
    int i1 = 0; float v1 = acc[0];
    #pragma unroll
    for (int k = 1; k < 8; ++k) if (acc[k] > v1) { v1 = acc[k]; i1 = k; }
    int i2 = -1; float v2 = -1e30f;
    #pragma unroll
    for (int k = 0; k < 8; ++k) if (k != i1 && acc[k] > v2) { v2 = acc[k]; i2 = k; }
    float t  = __expf(v2 - v1);
    float wa = 1.f / (1.f + t);
    float wb = t * wa;
    eidx[token * 2 + 0] = i1; eidx[token * 2 + 1] = i2;
    ewt [token * 2 + 0] = wa; ewt [token * 2 + 1] = wb;
  }
}

// ------- Scan: 1024 threads, 8 assigns/thread, wave shfl-scan + 8-thread fixup -------
__global__ __launch_bounds__(1024) void scan_k(
    const int* __restrict__ eidx, const float* __restrict__ ewt,
    int* __restrict__ counts, int* __restrict__ offsets,
    int* __restrict__ rowtok, float* __restrict__ rowwt, int* __restrict__ rowof,
    int* __restrict__ tile_e, int* __restrict__ tile_m0, int* __restrict__ tile_n)
{
  __shared__ int wtot[16][9];
  __shared__ int woff[16][9];
  __shared__ int soff[8];
  const int t = threadIdx.x, w = t >> 6, lane = t & 63;

  int4 a = ((const int4*)eidx)[t * 2];
  int4 b = ((const int4*)eidx)[t * 2 + 1];
  int my[8] = {a.x, a.y, a.z, a.w, b.x, b.y, b.z, b.w};
  int pre[8], local[8] = {};
  #pragma unroll
  for (int i = 0; i < 8; ++i) { pre[i] = local[my[i]]; local[my[i]]++; }

  int inc[8];
  #pragma unroll
  for (int e = 0; e < 8; ++e) inc[e] = local[e];
  #pragma unroll
  for (int d = 1; d < 64; d <<= 1) {
    #pragma unroll
    for (int e = 0; e < 8; ++e) {
      int v = __shfl_up(inc[e], d);
      if (lane >= d) inc[e] += v;
    }
  }
  if (lane == 63) {
    #pragma unroll
    for (int e = 0; e < 8; ++e) wtot[w][e] = inc[e];
  }
  __syncthreads();

  if (t < 8) {
    int e = t, run = 0;
    #pragma unroll
    for (int ww = 0; ww < 16; ++ww) { woff[ww][e] = run; run += wtot[ww][e]; }
    wtot[0][e] = run;   // total count (original [0][e] already consumed)
  }
  __syncthreads();

  if (t == 0) {
    int o = 0, tt = 0;
    for (int e = 0; e < 8; ++e) {
      int c = wtot[0][e];
      counts[e] = c;
      offsets[e] = o;
      soff[e] = o;
      int nt = (c + 127) >> 7;
      for (int i = 0; i < nt; ++i) { tile_e[tt] = e; tile_m0[tt] = i * 128; ++tt; }
      o += c;
    }
    tile_n[0] = tt;
  }
  __syncthreads();

  int base_[8];
  #pragma unroll
  for (int e = 0; e < 8; ++e) base_[e] = soff[e] + woff[w][e] + inc[e] - local[e];

  float4 wa4 = ((const float4*)ewt)[t * 2];
  float4 wb4 = ((const float4*)ewt)[t * 2 + 1];
  float wv[8] = {wa4.x, wa4.y, wa4.z, wa4.w, wb4.x, wb4.y, wb4.z, wb4.w};

  #pragma unroll
  for (int i = 0; i < 8; ++i) {
    int bb = t * 8 + i, e = my[i];
    int row = base_[e] + pre[i];
    rowtok[row] = bb >> 1;
    rowwt[row]  = wv[i];
    rowof[bb]   = row;
  }
}

// -------- Gather: block per row, x[token] -> bf16 Xe[row]. --------
__global__ __launch_bounds__(256) void gather_k(
    const float* __restrict__ x, const int* __restrict__ rowtok,
    unsigned short* __restrict__ Xe)
{
  const int row = blockIdx.x;
  const int token = rowtok[row];
  const float4* xr = (const float4*)(x + (size_t)token * D_MODEL);
  ushort4* dst = (ushort4*)(Xe + (size_t)row * D_MODEL);
  float4 v = xr[threadIdx.x];
  ushort4 o;
  o.x = f2b(v.x); o.y = f2b(v.y); o.z = f2b(v.z); o.w = f2b(v.w);
  dst[threadIdx.x] = o;
}

// ---------------- Segmented bf16 MFMA GEMM, 128x128 tile, BK=32 ----------------
// 16 KB LDS + XOR swizzle (R6, zero bank conflicts). launch_bounds(256,6):
// cap VGPR ~84 -> 6 waves/SIMD (6 blocks/CU vs 4).
// MODE 1: Hout = bf16(silu(A.Bt^T))   MODE 2: Hout = bf16(rowwt * A.Bt^T)
template<int K, int N, int NT_LOG2, int MODE>
__global__ __launch_bounds__(256, 6) void moe_gemm_k(
    const unsigned short* __restrict__ A,
    const unsigned short* __restrict__ Bt,
    unsigned short* __restrict__ Hout,
    const int* __restrict__ counts, const int* __restrict__ offsets,
    const float* __restrict__ rowwt,
    const int* __restrict__ tile_e, const int* __restrict__ tile_m0,
    const int* __restrict__ tile_n)
{
  const int t = blockIdx.x >> NT_LOG2;
  if (t >= tile_n[0]) return;
  const int e   = tile_e[t];
  const int m0  = tile_m0[t];
  const int n0  = (blockIdx.x & ((1 << NT_LOG2) - 1)) * 128;
  const int cnt = counts[e];
  const int base = offsets[e];

  __shared__ unsigned short lA[128 * 32];
  __shared__ unsigned short lB[128 * 32];

  const int tid = threadIdx.x;
  const int lane = tid & 63;
  const int wv = tid >> 6;
  const int wm = wv & 1, wn = wv >> 1;
  const int col = lane & 15, quad = lane >> 4;

  const unsigned short* Aseg = A + (size_t)base * K;
  const unsigned short* Bseg = Bt + (size_t)e * ((size_t)N * K);

  const int lrow = lane >> 2;
  const int gch  = (lane & 3) ^ ((lane >> 2) & 3) ^ ((lane >> 4) & 3);
  const int fsw  = (col & 3) ^ ((col >> 2) & 3);

  f32x4 acc[4][4] = {};

  for (int k0 = 0; k0 < K; k0 += 32) {
    __syncthreads();
    #pragma unroll
    for (int r = 0; r < 2; ++r) {
      int s = r * 4 + wv;
      int row = s * 16 + lrow;
      const char* gA = (const char*)Aseg + ((size_t)(m0 + row) * K + k0) * 2 + gch * 16;
      const char* gB = (const char*)Bseg + ((size_t)(n0 + row) * K + k0) * 2 + gch * 16;
      __builtin_amdgcn_global_load_lds((gl_void*)gA, (lds_void*)((char*)lA + s * 1024), 16, 0, 0);
      __builtin_amdgcn_global_load_lds((gl_void*)gB, (lds_void*)((char*)lB + s * 1024), 16, 0, 0);
    }
    __syncthreads();

    bf16x8 af[4], bfr[4];
    #pragma unroll
    for (int i = 0; i < 4; ++i) {
      int r = wm * 64 + i * 16 + col;
      int p = quad ^ fsw;
      af[i] = *(const bf16x8*)(lA + r * 32 + p * 8);
    }
    #pragma unroll
    for (int j = 0; j < 4; ++j) {
      int r = wn * 64 + j * 16 + col;
      int p = quad ^ fsw;
      bfr[j] = *(const bf16x8*)(lB + r * 32 + p * 8);
    }
    #pragma unroll
    for (int i = 0; i < 4; ++i)
      #pragma unroll
      for (int j = 0; j < 4; ++j)
        acc[i][j] = __builtin_amdgcn_mfma_f32_16x16x32_bf16(af[i], bfr[j], acc[i][j], 0, 0, 0);
  }

  // Epilogue. C/D layout: col = lane&15, row = quad*4 + reg  [m89/m91 verified]
  #pragma unroll
  for (int i = 0; i < 4; ++i) {
    #pragma unroll
    for (int reg = 0; reg < 4; ++reg) {
      int r = m0 + wm * 64 + i * 16 + quad * 4 + reg;
      if (r < cnt) {
        unsigned short* hrow = Hout + (size_t)(base + r) * N + (n0 + wn * 64 + col);
        if (MODE == 1) {
          #pragma unroll
          for (int j = 0; j < 4; ++j) {
            float v = acc[i][j][reg];
            float s = v / (1.f + __expf(-v));   // silu
            hrow[j * 16] = f2b(s);
          }
        } else {
          float wgt = rowwt[base + r];
          #pragma unroll
          for (int j = 0; j < 4; ++j)
            hrow[j * 16] = f2b(wgt * acc[i][j][reg]);
        }
      }
    }
  }
}

// ------- Combine: out[t] = Y[rowof[2t]] + Y[rowof[2t+1]] (weights pre-applied) -------
__global__ __launch_bounds__(256) void combine_k(
    const unsigned short* __restrict__ Y, const int* __restrict__ rowof,
    float* __restrict__ out)
{
  const int token = blockIdx.x;
  const int r1 = rowof[token * 2];
  const int r2 = rowof[token * 2 + 1];
  const int d4 = threadIdx.x;
  ushort4 a = *(const ushort4*)(Y + (size_t)r1 * D_MODEL + d4 * 4);
  ushort4 b = *(const ushort4*)(Y + (size_t)r2 * D_MODEL + d4 * 4);
  float4 o;
  o.x = b2f(a.x) + b2f(b.x);
  o.y = b2f(a.y) + b2f(b.y);
  o.z = b2f(a.z) + b2f(b.z);
  o.w = b2f(a.w) + b2f(b.w);
  *(float4*)(out + (size_t)token * D_MODEL + d4 * 4) = o;
}

extern "C" void kernel_launch(void* const* d_in, const int* in_sizes, int n_in,
                              void* d_out, int out_size, void* d_ws, size_t ws_size,
                              hipStream_t stream) {
  const float* x  = (const float*)d_in[0];
  const float* gw = (const float*)d_in[1];
  const float* w1 = (const float*)d_in[2];
  const float* w2 = (const float*)d_in[3];
  float* out = (float*)d_out;

  char* ws = (char*)d_ws;
  size_t off = 0;
  auto alloc = [&](size_t bytes) -> char* {
    char* p = ws + off; off += (bytes + 255) & ~(size_t)255; return p;
  };
  int*   ctrl    = (int*)alloc(1024);     // counts[8] | offsets[8] | tile_n | tiles
  int*   counts  = ctrl;
  int*   offsets = ctrl + 8;
  int*   tile_n  = ctrl + 16;
  int*   tile_e  = ctrl + 32;             // [MAXTILE]
  int*   tile_m0 = ctrl + 32 + MAXTILE;   // [MAXTILE]
  int*   eidx    = (int*)  alloc((size_t)NASSIGN * 4);
  float* ewt     = (float*)alloc((size_t)NASSIGN * 4);
  int*   rowtok  = (int*)  alloc((size_t)NASSIGN * 4);
  float* rowwt   = (float*)alloc((size_t)NASSIGN * 4);
  int*   rowof   = (int*)  alloc((size_t)NASSIGN * 4);
  unsigned short* Xe  = (unsigned short*)alloc((size_t)(NASSIGN + 128) * D_MODEL * 2);
  unsigned short* H   = (unsigned short*)alloc((size_t)(NASSIGN + 128) * D_FF * 2);
  unsigned short* Y   = (unsigned short*)alloc((size_t)(NASSIGN + 128) * D_MODEL * 2);
  unsigned short* w1t = (unsigned short*)alloc((size_t)N_EXP * D_MODEL * D_FF * 2);
  unsigned short* w2t = (unsigned short*)alloc((size_t)N_EXP * D_MODEL * D_FF * 2);

  prep_k<<<4096 + NTOK / 4, 256, 0, stream>>>(x, gw, w1, w2, w1t, w2t, eidx, ewt);
  scan_k<<<1, 1024, 0, stream>>>(eidx, ewt, counts, offsets, rowtok, rowwt, rowof,
                                 tile_e, tile_m0, tile_n);
  gather_k<<<NASSIGN, 256, 0, stream>>>(x, rowtok, Xe);

  moe_gemm_k<D_MODEL, D_FF, 4, 1><<<MAXTILE * 16, 256, 0, stream>>>(
      Xe, w1t, H, counts, offsets, rowwt, tile_e, tile_m0, tile_n);
  moe_gemm_k<D_FF, D_MODEL, 3, 2><<<MAXTILE * 8, 256, 0, stream>>>(
      H, w2t, Y, counts, offsets, rowwt, tile_e, tile_m0, tile_n);
  combine_k<<<NTOK, 256, 0, stream>>>(Y, rowof, out);
}

// Round 8
// 346.449 us; speedup vs baseline: 2.6509x; 2.6509x over previous
//
#include <hip/hip_runtime.h>
#include <cstdint>
#include <cstddef>

#define D_MODEL 1024
#define D_FF    2048
#define N_EXP   8
#define NTOK    4096          // B*S
#define NASSIGN (NTOK * 2)    // top-2
#define MAXTILE 72            // sum ceil(cnt_e/128) <= 64+7

typedef __bf16 bf16_t;
typedef bf16_t bf16x8 __attribute__((ext_vector_type(8)));
typedef float  f32x4  __attribute__((ext_vector_type(4)));

typedef __attribute__((address_space(3))) void       lds_void;
typedef const __attribute__((address_space(1))) void gl_void;

__device__ __forceinline__ unsigned short f2b(float f) {
  union { float f; unsigned u; } v; v.f = f;
  unsigned u = v.u;
  unsigned r = (u + 0x7FFFu + ((u >> 16) & 1u)) >> 16;  // RNE
  return (unsigned short)r;
}
__device__ __forceinline__ float b2f(unsigned short b) {
  union { unsigned u; float f; } v; v.u = ((unsigned)b) << 16; return v.f;
}

// ---------------- Prep: w1 transpose | w2 transpose | router, one launch ----------------
// Pair-pipelined transpose: 2 adjacent 64x64 tiles per block; all 8 global
// loads issued up-front; bf16 pairs packed in u32 LDS [64][33];
// 3 barriers per 2 tiles.
__device__ __forceinline__ void transpose_pair(
    const float* __restrict__ ein, unsigned short* __restrict__ eout,
    int R, int C, int c00, int r0, unsigned* T0, unsigned* T1, int tid)
{
  const int g = tid >> 4;        // 0..15
  const int m = tid & 15;        // 0..15
  const int sh = (g & 1) * 16;

  float4 v[2][4];
  #pragma unroll
  for (int t = 0; t < 2; ++t)
    #pragma unroll
    for (int i = 0; i < 4; ++i)
      v[t][i] = *(const float4*)(ein + (size_t)(r0 + i * 16 + g) * C + (c00 + t * 64) + m * 4);

  #pragma unroll
  for (int i = 0; i < 4; ++i) {
    unsigned lo = (unsigned)f2b(v[0][i].x) | ((unsigned)f2b(v[0][i].y) << 16);
    unsigned hi = (unsigned)f2b(v[0][i].z) | ((unsigned)f2b(v[0][i].w) << 16);
    unsigned* p = T0 + (i * 16 + g) * 33 + m * 2;
    p[0] = lo; p[1] = hi;
  }
  __syncthreads();
  #pragma unroll
  for (int i = 0; i < 4; ++i) {
    unsigned lo = (unsigned)f2b(v[1][i].x) | ((unsigned)f2b(v[1][i].y) << 16);
    unsigned hi = (unsigned)f2b(v[1][i].z) | ((unsigned)f2b(v[1][i].w) << 16);
    unsigned* p = T1 + (i * 16 + g) * 33 + m * 2;
    p[0] = lo; p[1] = hi;
  }
  #pragma unroll
  for (int i = 0; i < 4; ++i) {
    int c = i * 16 + g;
    ushort4 o;
    o.x = (unsigned short)(T0[(4 * m + 0) * 33 + (c >> 1)] >> sh);
    o.y = (unsigned short)(T0[(4 * m + 1) * 33 + (c >> 1)] >> sh);
    o.z = (unsigned short)(T0[(4 * m + 2) * 33 + (c >> 1)] >> sh);
    o.w = (unsigned short)(T0[(4 * m + 3) * 33 + (c >> 1)] >> sh);
    *(ushort4*)(eout + (size_t)(c00 + c) * R + r0 + m * 4) = o;
  }
  __syncthreads();
  #pragma unroll
  for (int i = 0; i < 4; ++i) {
    int c = i * 16 + g;
    ushort4 o;
    o.x = (unsigned short)(T1[(4 * m + 0) * 33 + (c >> 1)] >> sh);
    o.y = (unsigned short)(T1[(4 * m + 1) * 33 + (c >> 1)] >> sh);
    o.z = (unsigned short)(T1[(4 * m + 2) * 33 + (c >> 1)] >> sh);
    o.w = (unsigned short)(T1[(4 * m + 3) * 33 + (c >> 1)] >> sh);
    *(ushort4*)(eout + (size_t)(c00 + c + 64) * R + r0 + m * 4) = o;
  }
}

__global__ __launch_bounds__(256) void prep_k(
    const float* __restrict__ x, const float* __restrict__ gw,
    const float* __restrict__ w1, const float* __restrict__ w2,
    unsigned short* __restrict__ w1t, unsigned short* __restrict__ w2t,
    int* __restrict__ eidx, float* __restrict__ ewt)
{
  __shared__ unsigned T[2][64 * 33];
  const int bid = blockIdx.x;
  const int tid = threadIdx.x;

  if (bid < 2048) {
    // w1: [e][1024][2048] -> [e][2048][1024]; pairs along C: bx2 0..15, by 0..15
    int e = bid >> 8, rem = bid & 255;
    int bx2 = rem & 15, by = rem >> 4;
    transpose_pair(w1 + (size_t)e * D_MODEL * D_FF,
                   w1t + (size_t)e * D_MODEL * D_FF,
                   D_MODEL, D_FF, bx2 * 128, by * 64, T[0], T[1], tid);
    return;
  }
  if (bid < 4096) {
    // w2: [e][2048][1024] -> [e][1024][2048]; pairs along C: bx2 0..7, by 0..31
    int b = bid - 2048;
    int e = b >> 8, rem = b & 255;
    int bx2 = rem & 7, by = rem >> 3;
    transpose_pair(w2 + (size_t)e * D_MODEL * D_FF,
                   w2t + (size_t)e * D_MODEL * D_FF,
                   D_FF, D_MODEL, bx2 * 128, by * 64, T[0], T[1], tid);
    return;
  }
  // router: fp32 logits, top-2, softmax
  const int rb = bid - 4096;
  const int wv = tid >> 6, lane = tid & 63;
  const int token = rb * 4 + wv;
  const float4* xr4 = (const float4*)(x + (size_t)token * D_MODEL);
  const float4* gw4 = (const float4*)gw;

  float acc[8] = {};
  #pragma unroll
  for (int it = 0; it < 4; ++it) {
    float4 xv = xr4[it * 64 + lane];
    int d0 = it * 256 + lane * 4;
    #pragma unroll
    for (int i = 0; i < 4; ++i) {
      int d = d0 + i;
      float4 g0 = gw4[d * 2];
      float4 g1 = gw4[d * 2 + 1];
      float xs = (i == 0) ? xv.x : (i == 1) ? xv.y : (i == 2) ? xv.z : xv.w;
      acc[0] += xs * g0.x; acc[1] += xs * g0.y;
      acc[2] += xs * g0.z; acc[3] += xs * g0.w;
      acc[4] += xs * g1.x; acc[5] += xs * g1.y;
      acc[6] += xs * g1.z; acc[7] += xs * g1.w;
    }
  }
  #pragma unroll
  for (int m = 1; m < 64; m <<= 1) {
    #pragma unroll
    for (int k = 0; k < 8; ++k) acc[k] += __shfl_xor(acc[k], m);
  }
  if (lane == 0) {
    int i1 = 0; float v1 = acc[0];
    #pragma unroll
    for (int k = 1; k < 8; ++k) if (acc[k] > v1) { v1 = acc[k]; i1 = k; }
    int i2 = -1; float v2 = -1e30f;
    #pragma unroll
    for (int k = 0; k < 8; ++k) if (k != i1 && acc[k] > v2) { v2 = acc[k]; i2 = k; }
    float t  = __expf(v2 - v1);
    float wa = 1.f / (1.f + t);
    float wb = t * wa;
    eidx[token * 2 + 0] = i1; eidx[token * 2 + 1] = i2;
    ewt [token * 2 + 0] = wa; ewt [token * 2 + 1] = wb;
  }
}

// ------- Scan: 1024 threads, 8 assigns/thread, wave shfl-scan + 8-thread fixup -------
__global__ __launch_bounds__(1024) void scan_k(
    const int* __restrict__ eidx, const float* __restrict__ ewt,
    int* __restrict__ counts, int* __restrict__ offsets,
    int* __restrict__ rowtok, float* __restrict__ rowwt, int* __restrict__ rowof,
    int* __restrict__ tile_e, int* __restrict__ tile_m0, int* __restrict__ tile_n)
{
  __shared__ int wtot[16][9];
  __shared__ int woff[16][9];
  __shared__ int soff[8];
  const int t = threadIdx.x, w = t >> 6, lane = t & 63;

  int4 a = ((const int4*)eidx)[t * 2];
  int4 b = ((const int4*)eidx)[t * 2 + 1];
  int my[8] = {a.x, a.y, a.z, a.w, b.x, b.y, b.z, b.w};
  int pre[8], local[8] = {};
  #pragma unroll
  for (int i = 0; i < 8; ++i) { pre[i] = local[my[i]]; local[my[i]]++; }

  int inc[8];
  #pragma unroll
  for (int e = 0; e < 8; ++e) inc[e] = local[e];
  #pragma unroll
  for (int d = 1; d < 64; d <<= 1) {
    #pragma unroll
    for (int e = 0; e < 8; ++e) {
      int v = __shfl_up(inc[e], d);
      if (lane >= d) inc[e] += v;
    }
  }
  if (lane == 63) {
    #pragma unroll
    for (int e = 0; e < 8; ++e) wtot[w][e] = inc[e];
  }
  __syncthreads();

  if (t < 8) {
    int e = t, run = 0;
    #pragma unroll
    for (int ww = 0; ww < 16; ++ww) { woff[ww][e] = run; run += wtot[ww][e]; }
    wtot[0][e] = run;
  }
  __syncthreads();

  if (t == 0) {
    int o = 0, tt = 0;
    for (int e = 0; e < 8; ++e) {
      int c = wtot[0][e];
      counts[e] = c;
      offsets[e] = o;
      soff[e] = o;
      int nt = (c + 127) >> 7;
      for (int i = 0; i < nt; ++i) { tile_e[tt] = e; tile_m0[tt] = i * 128; ++tt; }
      o += c;
    }
    tile_n[0] = tt;
  }
  __syncthreads();

  int base_[8];
  #pragma unroll
  for (int e = 0; e < 8; ++e) base_[e] = soff[e] + woff[w][e] + inc[e] - local[e];

  float4 wa4 = ((const float4*)ewt)[t * 2];
  float4 wb4 = ((const float4*)ewt)[t * 2 + 1];
  float wv[8] = {wa4.x, wa4.y, wa4.z, wa4.w, wb4.x, wb4.y, wb4.z, wb4.w};

  #pragma unroll
  for (int i = 0; i < 8; ++i) {
    int bb = t * 8 + i, e = my[i];
    int row = base_[e] + pre[i];
    rowtok[row] = bb >> 1;
    rowwt[row]  = wv[i];
    rowof[bb]   = row;
  }
}

// -------- Gather: block per row, x[token] -> bf16 Xe[row]. --------
__global__ __launch_bounds__(256) void gather_k(
    const float* __restrict__ x, const int* __restrict__ rowtok,
    unsigned short* __restrict__ Xe)
{
  const int row = blockIdx.x;
  const int token = rowtok[row];
  const float4* xr = (const float4*)(x + (size_t)token * D_MODEL);
  ushort4* dst = (ushort4*)(Xe + (size_t)row * D_MODEL);
  float4 v = xr[threadIdx.x];
  ushort4 o;
  o.x = f2b(v.x); o.y = f2b(v.y); o.z = f2b(v.z); o.w = f2b(v.w);
  dst[threadIdx.x] = o;
}

// ---------------- Segmented bf16 MFMA GEMM, 128x128 tile, BK=32 ----------------
// 16 KB LDS + XOR swizzle (R6, zero bank conflicts).
// NOTE: plain __launch_bounds__(256). The (256,6) min-waves clause spilled
// the f32x4 acc[4][4] to scratch (VGPR 88->40, WRITE_SIZE 16MB->790MB,
// dur 70->390us) — never cap below the accumulator working set.
// MODE 1: Hout = bf16(silu(A.Bt^T))   MODE 2: Hout = bf16(rowwt * A.Bt^T)
template<int K, int N, int NT_LOG2, int MODE>
__global__ __launch_bounds__(256) void moe_gemm_k(
    const unsigned short* __restrict__ A,
    const unsigned short* __restrict__ Bt,
    unsigned short* __restrict__ Hout,
    const int* __restrict__ counts, const int* __restrict__ offsets,
    const float* __restrict__ rowwt,
    const int* __restrict__ tile_e, const int* __restrict__ tile_m0,
    const int* __restrict__ tile_n)
{
  const int t = blockIdx.x >> NT_LOG2;
  if (t >= tile_n[0]) return;
  const int e   = tile_e[t];
  const int m0  = tile_m0[t];
  const int n0  = (blockIdx.x & ((1 << NT_LOG2) - 1)) * 128;
  const int cnt = counts[e];
  const int base = offsets[e];

  __shared__ unsigned short lA[128 * 32];
  __shared__ unsigned short lB[128 * 32];

  const int tid = threadIdx.x;
  const int lane = tid & 63;
  const int wv = tid >> 6;
  const int wm = wv & 1, wn = wv >> 1;
  const int col = lane & 15, quad = lane >> 4;

  const unsigned short* Aseg = A + (size_t)base * K;
  const unsigned short* Bseg = Bt + (size_t)e * ((size_t)N * K);

  const int lrow = lane >> 2;
  const int gch  = (lane & 3) ^ ((lane >> 2) & 3) ^ ((lane >> 4) & 3);
  const int fsw  = (col & 3) ^ ((col >> 2) & 3);

  f32x4 acc[4][4] = {};

  for (int k0 = 0; k0 < K; k0 += 32) {
    __syncthreads();
    #pragma unroll
    for (int r = 0; r < 2; ++r) {
      int s = r * 4 + wv;
      int row = s * 16 + lrow;
      const char* gA = (const char*)Aseg + ((size_t)(m0 + row) * K + k0) * 2 + gch * 16;
      const char* gB = (const char*)Bseg + ((size_t)(n0 + row) * K + k0) * 2 + gch * 16;
      __builtin_amdgcn_global_load_lds((gl_void*)gA, (lds_void*)((char*)lA + s * 1024), 16, 0, 0);
      __builtin_amdgcn_global_load_lds((gl_void*)gB, (lds_void*)((char*)lB + s * 1024), 16, 0, 0);
    }
    __syncthreads();

    bf16x8 af[4], bfr[4];
    #pragma unroll
    for (int i = 0; i < 4; ++i) {
      int r = wm * 64 + i * 16 + col;
      int p = quad ^ fsw;
      af[i] = *(const bf16x8*)(lA + r * 32 + p * 8);
    }
    #pragma unroll
    for (int j = 0; j < 4; ++j) {
      int r = wn * 64 + j * 16 + col;
      int p = quad ^ fsw;
      bfr[j] = *(const bf16x8*)(lB + r * 32 + p * 8);
    }
    #pragma unroll
    for (int i = 0; i < 4; ++i)
      #pragma unroll
      for (int j = 0; j < 4; ++j)
        acc[i][j] = __builtin_amdgcn_mfma_f32_16x16x32_bf16(af[i], bfr[j], acc[i][j], 0, 0, 0);
  }

  // Epilogue. C/D layout: col = lane&15, row = quad*4 + reg  [m89/m91 verified]
  #pragma unroll
  for (int i = 0; i < 4; ++i) {
    #pragma unroll
    for (int reg = 0; reg < 4; ++reg) {
      int r = m0 + wm * 64 + i * 16 + quad * 4 + reg;
      if (r < cnt) {
        unsigned short* hrow = Hout + (size_t)(base + r) * N + (n0 + wn * 64 + col);
        if (MODE == 1) {
          #pragma unroll
          for (int j = 0; j < 4; ++j) {
            float v = acc[i][j][reg];
            float s = v / (1.f + __expf(-v));   // silu
            hrow[j * 16] = f2b(s);
          }
        } else {
          float wgt = rowwt[base + r];
          #pragma unroll
          for (int j = 0; j < 4; ++j)
            hrow[j * 16] = f2b(wgt * acc[i][j][reg]);
        }
      }
    }
  }
}

// ------- Combine: out[t] = Y[rowof[2t]] + Y[rowof[2t+1]] (weights pre-applied) -------
__global__ __launch_bounds__(256) void combine_k(
    const unsigned short* __restrict__ Y, const int* __restrict__ rowof,
    float* __restrict__ out)
{
  const int token = blockIdx.x;
  const int r1 = rowof[token * 2];
  const int r2 = rowof[token * 2 + 1];
  const int d4 = threadIdx.x;
  ushort4 a = *(const ushort4*)(Y + (size_t)r1 * D_MODEL + d4 * 4);
  ushort4 b = *(const ushort4*)(Y + (size_t)r2 * D_MODEL + d4 * 4);
  float4 o;
  o.x = b2f(a.x) + b2f(b.x);
  o.y = b2f(a.y) + b2f(b.y);
  o.z = b2f(a.z) + b2f(b.z);
  o.w = b2f(a.w) + b2f(b.w);
  *(float4*)(out + (size_t)token * D_MODEL + d4 * 4) = o;
}

extern "C" void kernel_launch(void* const* d_in, const int* in_sizes, int n_in,
                              void* d_out, int out_size, void* d_ws, size_t ws_size,
                              hipStream_t stream) {
  const float* x  = (const float*)d_in[0];
  const float* gw = (const float*)d_in[1];
  const float* w1 = (const float*)d_in[2];
  const float* w2 = (const float*)d_in[3];
  float* out = (float*)d_out;

  char* ws = (char*)d_ws;
  size_t off = 0;
  auto alloc = [&](size_t bytes) -> char* {
    char* p = ws + off; off += (bytes + 255) & ~(size_t)255; return p;
  };
  int*   ctrl    = (int*)alloc(1024);     // counts[8] | offsets[8] | tile_n | tiles
  int*   counts  = ctrl;
  int*   offsets = ctrl + 8;
  int*   tile_n  = ctrl + 16;
  int*   tile_e  = ctrl + 32;             // [MAXTILE]
  int*   tile_m0 = ctrl + 32 + MAXTILE;   // [MAXTILE]
  int*   eidx    = (int*)  alloc((size_t)NASSIGN * 4);
  float* ewt     = (float*)alloc((size_t)NASSIGN * 4);
  int*   rowtok  = (int*)  alloc((size_t)NASSIGN * 4);
  float* rowwt   = (float*)alloc((size_t)NASSIGN * 4);
  int*   rowof   = (int*)  alloc((size_t)NASSIGN * 4);
  unsigned short* Xe  = (unsigned short*)alloc((size_t)(NASSIGN + 128) * D_MODEL * 2);
  unsigned short* H   = (unsigned short*)alloc((size_t)(NASSIGN + 128) * D_FF * 2);
  unsigned short* Y   = (unsigned short*)alloc((size_t)(NASSIGN + 128) * D_MODEL * 2);
  unsigned short* w1t = (unsigned short*)alloc((size_t)N_EXP * D_MODEL * D_FF * 2);
  unsigned short* w2t = (unsigned short*)alloc((size_t)N_EXP * D_MODEL * D_FF * 2);

  prep_k<<<4096 + NTOK / 4, 256, 0, stream>>>(x, gw, w1, w2, w1t, w2t, eidx, ewt);
  scan_k<<<1, 1024, 0, stream>>>(eidx, ewt, counts, offsets, rowtok, rowwt, rowof,
                                 tile_e, tile_m0, tile_n);
  gather_k<<<NASSIGN, 256, 0, stream>>>(x, rowtok, Xe);

  moe_gemm_k<D_MODEL, D_FF, 4, 1><<<MAXTILE * 16, 256, 0, stream>>>(
      Xe, w1t, H, counts, offsets, rowwt, tile_e, tile_m0, tile_n);
  moe_gemm_k<D_FF, D_MODEL, 3, 2><<<MAXTILE * 8, 256, 0, stream>>>(
      H, w2t, Y, counts, offsets, rowwt, tile_e, tile_m0, tile_n);
  combine_k<<<NTOK, 256, 0, stream>>>(Y, rowof, out);
}